// Round 5
// baseline (354.311 us; speedup 1.0000x reference)
//
#include <hip/hip_runtime.h>
#include <cstdint>
#include <cstddef>

#define F_ALPHA 0.5f
#define THRESH  0.5f
#define EPS8    1e-8f
#define EPS7    1e-7f
#define MAXM    64
#define CCLS    21
#define NBUCK   1024   // 32x32 Morton buckets

// Morton interleave of 5-bit (bx, by) -> 10-bit bucket
__device__ __forceinline__ unsigned morton_bucket(float4 d)
{
    float cx = 0.5f * (d.x + d.z);
    float cy = 0.5f * (d.y + d.w);
    int bx = min(max((int)(cx * 32.0f), 0), 31);
    int by = min(max((int)(cy * 32.0f), 0), 31);
    unsigned r = 0;
    #pragma unroll
    for (int i = 0; i < 5; i++)
        r |= (((unsigned)(bx >> i) & 1u) << (2 * i))
           | (((unsigned)(by >> i) & 1u) << (2 * i + 1));
    return r;
}

// ---------------------------------------------------------------------------
// Sort pipeline: priors in Morton order -> blocks are ~0.1x0.1 regions ->
// 2D block-uniform GT rejection in match_kernel.
// ---------------------------------------------------------------------------
__global__ __launch_bounds__(256)
void histo_kernel(const float4* __restrict__ dbox, int* __restrict__ hist,
                  unsigned long long* __restrict__ bpkey, int P, int nbp)
{
    int i = blockIdx.x * 256 + threadIdx.x;
    if (i < nbp) bpkey[i] = 0x00000000FFFFFFFFull;   // key(iou=0, p=0) fallback
    if (i < P) atomicAdd(&hist[morton_bucket(dbox[i])], 1);
}

__global__ __launch_bounds__(1024)
void scan_kernel(const int* __restrict__ hist, int* __restrict__ offs)
{
    __shared__ int tmp[NBUCK];
    int t = threadIdx.x;
    int h = hist[t];
    int v = h;
    tmp[t] = v;
    __syncthreads();
    for (int d = 1; d < NBUCK; d <<= 1) {
        int u = (t >= d) ? tmp[t - d] : 0;
        __syncthreads();
        v += u;
        tmp[t] = v;
        __syncthreads();
    }
    offs[t] = v - h;    // exclusive prefix
}

__global__ __launch_bounds__(256)
void scatter_kernel(const float4* __restrict__ dbox, int* __restrict__ offs,
                    float4* __restrict__ sbox, int* __restrict__ sperm, int P)
{
    int p = blockIdx.x * 256 + threadIdx.x;
    if (p < P) {
        float4 d = dbox[p];
        int pos = atomicAdd(&offs[morton_bucket(d)], 1);
        sbox[pos] = d;
        sperm[pos] = p;
    }
}

// ---------------------------------------------------------------------------
// Kernel A: matching on Morton-sorted priors.
// Per active GT: IoU + packed-u64 wave shuffle-max (no in-loop barriers,
// no LDS score matrix). 3 barriers total. Exact global tie-break via ~orig.
// ---------------------------------------------------------------------------
__global__ __launch_bounds__(256)
void match_kernel(const float4* __restrict__ sbox, const int* __restrict__ sperm,
                  const float4* __restrict__ gt,
                  unsigned long long* __restrict__ bpkey,
                  unsigned char* __restrict__ match, int P, int M)
{
    __shared__ float4 tb[MAXM];
    __shared__ float  tarea[MAXM];
    __shared__ unsigned long long wavemax[4 * MAXM];
    __shared__ float  redv[4 * 4];          // per-wave minx,maxz,miny,maxw
    __shared__ unsigned amask_lo, amask_hi;

    const int t = threadIdx.x;
    const int b = blockIdx.y;
    const int p0 = blockIdx.x * 256;
    const int p = p0 + t;
    const bool valid = (p < P);
    const int wv = t >> 6, lane = t & 63;

    if (t < M) {
        float4 g = gt[(size_t)b * M + t];
        tb[t] = g;
        tarea[t] = (g.z - g.x) * (g.w - g.y);
    }
    wavemax[t] = 0ull;                       // 4*64 slots, one per thread

    float4 d = valid ? sbox[p] : make_float4(2.f, 2.f, 2.f, 2.f);
    const unsigned orig = valid ? (unsigned)sperm[p] : 0u;

    // block 2D extent over valid lanes (invalid sentinel shrinks nothing:
    // x=2 > any min candidate? min uses +inf/-inf instead)
    float mnx = valid ? d.x : 1e30f, mxz = valid ? d.z : -1e30f;
    float mny = valid ? d.y : 1e30f, mxw = valid ? d.w : -1e30f;
    for (int o = 32; o > 0; o >>= 1) {
        mnx = fminf(mnx, __shfl_xor(mnx, o, 64));
        mxz = fmaxf(mxz, __shfl_xor(mxz, o, 64));
        mny = fminf(mny, __shfl_xor(mny, o, 64));
        mxw = fmaxf(mxw, __shfl_xor(mxw, o, 64));
    }
    if (lane == 0) {
        redv[wv * 4 + 0] = mnx; redv[wv * 4 + 1] = mxz;
        redv[wv * 4 + 2] = mny; redv[wv * 4 + 3] = mxw;
    }
    __syncthreads();                         // barrier 1

    const float bminx = fminf(fminf(redv[0], redv[4]),  fminf(redv[8],  redv[12]));
    const float bmaxz = fmaxf(fmaxf(redv[1], redv[5]),  fmaxf(redv[9],  redv[13]));
    const float bminy = fminf(fminf(redv[2], redv[6]),  fminf(redv[10], redv[14]));
    const float bmaxw = fmaxf(fmaxf(redv[3], redv[7]),  fmaxf(redv[11], redv[15]));

    // active-GT ballot: GT must overlap block extent in BOTH axes.
    // t<M lanes all live in wave 0 (M<=64), so wave-0 ballot is the mask.
    bool act = (t < M) && (tb[t].x < bmaxz) && (tb[t].z > bminx)
                       && (tb[t].y < bmaxw) && (tb[t].w > bminy);
    unsigned long long bal = __ballot(act);
    if (t == 0) { amask_lo = (unsigned)bal; amask_hi = (unsigned)(bal >> 32); }
    __syncthreads();                         // barrier 2
    const unsigned long long amask = ((unsigned long long)amask_hi << 32) | amask_lo;

    const float darea = (d.z - d.x) * (d.w - d.y);
    float best = -1.0f;     // strict > => first active m on ties; 0-iou rows harmless
    int   bm = 0;

    for (int m = 0; m < M; m++) {
        if (!((amask >> m) & 1)) continue;   // block-uniform scalar skip
        float4 g = tb[m];
        float lx = fmaxf(d.x, g.x), ly = fmaxf(d.y, g.y);
        float rx = fminf(d.z, g.z), ry = fminf(d.w, g.w);
        float ww = fmaxf(rx - lx, 0.f), hh = fmaxf(ry - ly, 0.f);
        float inter = ww * hh;
        // fast rcp: feeds compares only (bt/bp argmax), 1-ulp harmless
        float iou = inter * __builtin_amdgcn_rcpf(darea + tarea[m] - inter);
        if (iou > best) { best = iou; bm = m; }
        // bp wave-max of (iou_bits, ~orig): max iou, tie -> min orig (exact)
        unsigned long long key = (iou > 0.0f)
            ? (((unsigned long long)__float_as_uint(iou) << 32)
               | (unsigned long long)(0xFFFFFFFFu - orig))
            : 0ull;
        for (int o = 32; o > 0; o >>= 1) {
            unsigned long long other = __shfl_xor(key, o, 64);
            key = (other > key) ? other : key;
        }
        if (lane == 0) wavemax[wv * MAXM + m] = key;
    }
    __syncthreads();                         // barrier 3

    if (t < M) {
        unsigned long long k0 = wavemax[0 * MAXM + t];
        unsigned long long k1 = wavemax[1 * MAXM + t];
        unsigned long long k2 = wavemax[2 * MAXM + t];
        unsigned long long k3 = wavemax[3 * MAXM + t];
        unsigned long long k = k0 > k1 ? k0 : k1;
        unsigned long long k23 = k2 > k3 ? k2 : k3;
        k = k > k23 ? k : k23;
        if (k != 0ull) atomicMax(&bpkey[(size_t)b * M + t], k);
    }

    if (valid) {
        unsigned char code = (unsigned char)((best >= THRESH ? 0x40 : 0) | bm);
        match[(size_t)b * P + orig] = code;
    }
}

// ---------------------------------------------------------------------------
// Kernel B: force-match each GT's best prior (sequential: last-wins scatter).
// ---------------------------------------------------------------------------
__global__ void force_kernel(const unsigned long long* __restrict__ bpkey,
                             unsigned char* __restrict__ match, int P, int M)
{
    int b = blockIdx.x;
    if (threadIdx.x == 0) {
        for (int j = 0; j < M; j++) {
            unsigned p = 0xFFFFFFFFu - (unsigned)(bpkey[(size_t)b * M + j] & 0xFFFFFFFFull);
            match[(size_t)b * P + p] = (unsigned char)(0x80 | j);
        }
    }
}

// ---------------------------------------------------------------------------
// Kernel C: focal loss on every anchor (conf via coalesced LDS staging) +
// GIoU on positives. Per-block partials to private slots (no atomics).
// ---------------------------------------------------------------------------
__global__ __launch_bounds__(256)
void loss_kernel(const float4* __restrict__ locp,
                 const float*  __restrict__ conf,
                 const float4* __restrict__ dbox,
                 const float4* __restrict__ gt,
                 const int*    __restrict__ gtl,
                 const unsigned char* __restrict__ match,
                 double* __restrict__ partS,
                 int*    __restrict__ partC,
                 int P, int M)
{
    __shared__ float    scf[256 * CCLS];
    __shared__ float4   tb[MAXM];
    __shared__ int      tl[MAXM];
    __shared__ double   sv[4];
    __shared__ int      sc[4];

    const int t = threadIdx.x;
    const int b = blockIdx.y;
    const int p0 = blockIdx.x * 256;
    const int p = p0 + t;

    if (t < M) {
        tb[t] = gt[(size_t)b * M + t];
        tl[t] = gtl[(size_t)b * M + t];
    }

    const int cnt = min(256, P - p0);
    const int nf = cnt * CCLS;
    const float* src = conf + ((size_t)b * P + p0) * CCLS;
    {
        const int n4 = nf >> 2;
        const float4* s4 = (const float4*)src;
        float4* d4 = (float4*)scf;
        for (int i = t; i < n4; i += 256) d4[i] = s4[i];
        for (int i = (n4 << 2) + t; i < nf; i += 256) scf[i] = src[i];
    }
    __syncthreads();

    double acc = 0.0;
    int cnt_pos = 0;
    if (p < P) {
        unsigned char code = match[(size_t)b * P + p];
        int  idx = code & 0x3F;
        bool pos = (code & 0xC0) != 0;
        int  lbl = pos ? tl[idx] : 0;

        const float* x = scf + t * CCLS;
        float mx = -1e30f;
        #pragma unroll
        for (int c = 0; c < CCLS; c++) mx = fmaxf(mx, x[c]);
        float sum = 0.f;
        #pragma unroll
        for (int c = 0; c < CCLS; c++) sum += expf(x[c] - mx);
        float ce = (mx + logf(sum)) - x[lbl];
        float pt = expf(-ce);
        float om = 1.f - pt;
        acc = (double)(F_ALPHA * om * sqrtf(om) * ce);

        if (pos) {
            cnt_pos = 1;
            float4 d = dbox[p];
            float dw = d.z - d.x, dh = d.w - d.y;
            float dcx = d.x + dw * 0.5f, dcy = d.y + dh * 0.5f;
            float4 g = tb[idx];
            float gw = g.z - g.x, gh = g.w - g.y;
            float gcx = g.x + gw * 0.5f, gcy = g.y + gh * 0.5f;
            float ex = (gcx - dcx) / (dw + EPS8);
            float ey = (gcy - dcy) / (dh + EPS8);
            float ew = logf(gw / (dw + EPS8) + EPS8);
            float eh = logf(gh / (dh + EPS8) + EPS8);
            float tcx = ex * dw + dcx, tcy = ey * dh + dcy;
            float tw = expf(ew) * dw,  th = expf(eh) * dh;
            float t0 = tcx - tw * 0.5f, t1 = tcy - th * 0.5f;
            float t2 = tcx + tw * 0.5f, t3 = tcy + th * 0.5f;
            float4 l = locp[(size_t)b * P + p];
            float pcx = l.x * dw + dcx, pcy = l.y * dh + dcy;
            float pw = expf(l.z) * dw,  ph = expf(l.w) * dh;
            float q0 = pcx - pw * 0.5f, q1 = pcy - ph * 0.5f;
            float q2 = pcx + pw * 0.5f, q3 = pcy + ph * 0.5f;
            float ix0 = fmaxf(q0, t0), iy0 = fmaxf(q1, t1);
            float ix1 = fminf(q2, t2), iy1 = fminf(q3, t3);
            float iw = fmaxf(ix1 - ix0, 0.f), ih = fmaxf(iy1 - iy0, 0.f);
            float inter = iw * ih;
            float pa = (q2 - q0) * (q3 - q1);
            float ta = (t2 - t0) * (t3 - t1);
            float uni = pa + ta - inter;
            float iou = inter / (uni + EPS7);
            float e0 = fminf(q0, t0), e1 = fminf(q1, t1);
            float e2 = fmaxf(q2, t2), e3 = fmaxf(q3, t3);
            float ewd = fmaxf(e2 - e0, 0.f), ehd = fmaxf(e3 - e1, 0.f);
            float encl = ewd * ehd;
            float giou = iou - (encl - uni) / (encl + EPS7);
            acc += (double)(1.f - giou);
        }
    }

    for (int o = 32; o > 0; o >>= 1) {
        acc += __shfl_down(acc, o, 64);
        cnt_pos += __shfl_down(cnt_pos, o, 64);
    }
    int w = t >> 6, lane = t & 63;
    if (lane == 0) { sv[w] = acc; sc[w] = cnt_pos; }
    __syncthreads();
    if (t == 0) {
        int slot = blockIdx.y * gridDim.x + blockIdx.x;
        partS[slot] = sv[0] + sv[1] + sv[2] + sv[3];
        partC[slot] = sc[0] + sc[1] + sc[2] + sc[3];
    }
}

__global__ __launch_bounds__(256)
void final_kernel(const double* __restrict__ partS,
                  const int*    __restrict__ partC,
                  float* __restrict__ out, int n)
{
    __shared__ double sv[4];
    __shared__ long long sc[4];
    const int t = threadIdx.x;
    double a = 0.0; long long c = 0;
    for (int i = t; i < n; i += 256) { a += partS[i]; c += partC[i]; }
    for (int o = 32; o > 0; o >>= 1) {
        a += __shfl_down(a, o, 64);
        c += __shfl_down(c, o, 64);
    }
    int w = t >> 6, lane = t & 63;
    if (lane == 0) { sv[w] = a; sc[w] = c; }
    __syncthreads();
    if (t == 0) {
        double s = sv[0] + sv[1] + sv[2] + sv[3];
        long long np = sc[0] + sc[1] + sc[2] + sc[3];
        out[0] = (np == 0) ? 0.0f : (float)(s / (double)np);
    }
}

// ---------------------------------------------------------------------------
extern "C" void kernel_launch(void* const* d_in, const int* in_sizes, int n_in,
                              void* d_out, int out_size, void* d_ws, size_t ws_size,
                              hipStream_t stream)
{
    const float* locp = (const float*)d_in[0];   // [B,P,4]
    const float* conf = (const float*)d_in[1];   // [B,P,C]
    const float* dbox = (const float*)d_in[2];   // [P,4]
    const float* gt   = (const float*)d_in[3];   // [B,M,4]
    const int*   gtl  = (const int*)d_in[4];     // [B,M]

    const int P  = in_sizes[2] / 4;
    const long long BP = (long long)in_sizes[0] / 4;
    const int B  = (int)(BP / P);
    const int M  = in_sizes[4] / B;

    const int nblk = (P + 255) / 256;
    const int nPart = nblk * B;

    // ws layout (desc. alignment):
    char* ws = (char*)d_ws;
    size_t off = 0;
    float4* sbox = (float4*)(ws + off);           off += (size_t)P * 16;
    unsigned long long* bpkey = (unsigned long long*)(ws + off); off += (size_t)B * M * 8;
    double* partS = (double*)(ws + off);          off += (size_t)nPart * 8;
    int* hist  = (int*)(ws + off);                off += (size_t)NBUCK * 4;
    int* offs  = (int*)(ws + off);                off += (size_t)NBUCK * 4;
    int* sperm = (int*)(ws + off);                off += (size_t)P * 4;
    int* partC = (int*)(ws + off);                off += (size_t)nPart * 4;
    unsigned char* match = (unsigned char*)(ws + off);

    hipMemsetAsync(hist, 0, NBUCK * 4, stream);

    dim3 grid(nblk, B);
    histo_kernel<<<nblk, 256, 0, stream>>>((const float4*)dbox, hist, bpkey, P, B * M);
    scan_kernel<<<1, NBUCK, 0, stream>>>(hist, offs);
    scatter_kernel<<<nblk, 256, 0, stream>>>((const float4*)dbox, offs, sbox, sperm, P);
    match_kernel<<<grid, 256, 0, stream>>>(sbox, sperm, (const float4*)gt,
                                           bpkey, match, P, M);
    force_kernel<<<B, 64, 0, stream>>>(bpkey, match, P, M);
    loss_kernel<<<grid, 256, 0, stream>>>((const float4*)locp, conf,
                                          (const float4*)dbox, (const float4*)gt,
                                          gtl, match, partS, partC, P, M);
    final_kernel<<<1, 256, 0, stream>>>(partS, partC, (float*)d_out, nPart);
}

// Round 6
// 325.760 us; speedup vs baseline: 1.0876x; 1.0876x over previous
//
#include <hip/hip_runtime.h>
#include <cstdint>
#include <cstddef>

#define F_ALPHA 0.5f
#define THRESH  0.5f
#define EPS8    1e-8f
#define EPS7    1e-7f
#define MAXM    64
#define CCLS    21
#define NBUCK   1024   // 32x32 Morton buckets
#define MAXBLK  512    // cap on number of 256-prior chunks (P <= 128K)

// Morton interleave of 5-bit (bx, by) -> 10-bit bucket
__device__ __forceinline__ unsigned morton_bucket(float4 d)
{
    float cx = 0.5f * (d.x + d.z);
    float cy = 0.5f * (d.y + d.w);
    int bx = min(max((int)(cx * 32.0f), 0), 31);
    int by = min(max((int)(cy * 32.0f), 0), 31);
    unsigned r = 0;
    #pragma unroll
    for (int i = 0; i < 5; i++)
        r |= (((unsigned)(bx >> i) & 1u) << (2 * i))
           | (((unsigned)(by >> i) & 1u) << (2 * i + 1));
    return r;
}

// ---------------------------------------------------------------------------
// Sort pipeline: priors in Morton order -> blocks are compact 2D regions.
// ---------------------------------------------------------------------------
__global__ __launch_bounds__(256)
void histo_kernel(const float4* __restrict__ dbox, int* __restrict__ hist, int P)
{
    int i = blockIdx.x * 256 + threadIdx.x;
    if (i < P) atomicAdd(&hist[morton_bucket(dbox[i])], 1);
}

__global__ __launch_bounds__(1024)
void scan_kernel(const int* __restrict__ hist, int* __restrict__ offs)
{
    __shared__ int tmp[NBUCK];
    int t = threadIdx.x;
    int h = hist[t];
    int v = h;
    tmp[t] = v;
    __syncthreads();
    for (int d = 1; d < NBUCK; d <<= 1) {
        int u = (t >= d) ? tmp[t - d] : 0;
        __syncthreads();
        v += u;
        tmp[t] = v;
        __syncthreads();
    }
    offs[t] = v - h;    // exclusive prefix
}

__global__ __launch_bounds__(256)
void scatter_kernel(const float4* __restrict__ dbox, int* __restrict__ offs,
                    float4* __restrict__ sbox, int* __restrict__ sperm, int P)
{
    int p = blockIdx.x * 256 + threadIdx.x;
    if (p < P) {
        float4 d = dbox[p];
        int pos = atomicAdd(&offs[morton_bucket(d)], 1);
        sbox[pos] = d;
        sperm[pos] = p;
    }
}

// ---------------------------------------------------------------------------
// Per-chunk (256 sorted priors) bounding extent: (minx, miny, maxz, maxw).
// ---------------------------------------------------------------------------
__global__ __launch_bounds__(256)
void extent_kernel(const float4* __restrict__ sbox, float4* __restrict__ bext, int P)
{
    __shared__ float red[4][4];
    const int t = threadIdx.x;
    const int p = blockIdx.x * 256 + t;
    const bool valid = (p < P);
    float4 d = valid ? sbox[p] : make_float4(0.f, 0.f, 0.f, 0.f);
    float mnx = valid ? d.x : 1e30f, mny = valid ? d.y : 1e30f;
    float mxz = valid ? d.z : -1e30f, mxw = valid ? d.w : -1e30f;
    for (int o = 32; o > 0; o >>= 1) {
        mnx = fminf(mnx, __shfl_xor(mnx, o, 64));
        mny = fminf(mny, __shfl_xor(mny, o, 64));
        mxz = fmaxf(mxz, __shfl_xor(mxz, o, 64));
        mxw = fmaxf(mxw, __shfl_xor(mxw, o, 64));
    }
    const int wv = t >> 6, lane = t & 63;
    if (lane == 0) {
        red[wv][0] = mnx; red[wv][1] = mny; red[wv][2] = mxz; red[wv][3] = mxw;
    }
    __syncthreads();
    if (t == 0) {
        float4 e;
        e.x = fminf(fminf(red[0][0], red[1][0]), fminf(red[2][0], red[3][0]));
        e.y = fminf(fminf(red[0][1], red[1][1]), fminf(red[2][1], red[3][1]));
        e.z = fmaxf(fmaxf(red[0][2], red[1][2]), fmaxf(red[2][2], red[3][2]));
        e.w = fmaxf(fmaxf(red[0][3], red[1][3]), fmaxf(red[2][3], red[3][3]));
        bext[blockIdx.x] = e;
    }
}

// ---------------------------------------------------------------------------
// bt kernel: per-prior best GT. Morton-gated, NO in-loop reductions,
// 1 barrier. grid = (nblk, B).
// ---------------------------------------------------------------------------
__global__ __launch_bounds__(256)
void bt_kernel(const float4* __restrict__ sbox, const int* __restrict__ sperm,
               const float4* __restrict__ gt, const float4* __restrict__ bext,
               unsigned char* __restrict__ match, int P, int M)
{
    __shared__ float4 tb[MAXM];
    __shared__ float  tarea[MAXM];
    __shared__ unsigned amask_lo, amask_hi;

    const int t = threadIdx.x;
    const int b = blockIdx.y;
    const int p0 = blockIdx.x * 256;
    const int p = p0 + t;
    const bool valid = (p < P);

    const float4 e = bext[blockIdx.x];

    bool act = false;
    if (t < M) {
        float4 g = gt[(size_t)b * M + t];
        tb[t] = g;
        tarea[t] = (g.z - g.x) * (g.w - g.y);
        act = (g.x < e.z) && (g.z > e.x) && (g.y < e.w) && (g.w > e.y);
    }
    // t<M lanes all in wave 0 (M<=64): wave-0 ballot is the block mask
    unsigned long long bal = __ballot(act);
    if (t == 0) { amask_lo = (unsigned)bal; amask_hi = (unsigned)(bal >> 32); }

    float4 d = valid ? sbox[p] : make_float4(2.f, 2.f, 2.f, 2.f);
    const unsigned orig = valid ? (unsigned)sperm[p] : 0u;
    const float darea = (d.z - d.x) * (d.w - d.y);
    __syncthreads();
    const unsigned long long amask = ((unsigned long long)amask_hi << 32) | amask_lo;

    float best = -1.0f;   // strict > => first active m on ties; skipped rows have iou=0
    int   bm = 0;
    for (int m = 0; m < M; m++) {
        if (!((amask >> m) & 1)) continue;     // block-uniform scalar skip
        float4 g = tb[m];
        float lx = fmaxf(d.x, g.x), ly = fmaxf(d.y, g.y);
        float rx = fminf(d.z, g.z), ry = fminf(d.w, g.w);
        float ww = fmaxf(rx - lx, 0.f), hh = fmaxf(ry - ly, 0.f);
        float inter = ww * hh;
        // fast rcp: feeds compares only; bit-identical expression in bp_kernel
        float iou = inter * __builtin_amdgcn_rcpf(darea + tarea[m] - inter);
        if (iou > best) { best = iou; bm = m; }
    }

    if (valid) {
        unsigned char code = (unsigned char)((best >= THRESH ? 0x40 : 0) | bm);
        match[(size_t)b * P + orig] = code;
    }
}

// ---------------------------------------------------------------------------
// bp kernel: per-GT best prior. One block per (m, b). Extent-gated chunks,
// thread-local key max, single wave+LDS reduction, plain store (no atomics).
// ---------------------------------------------------------------------------
__global__ __launch_bounds__(256)
void bp_kernel(const float4* __restrict__ sbox, const int* __restrict__ sperm,
               const float4* __restrict__ gt, const float4* __restrict__ bext,
               unsigned long long* __restrict__ bpkey, int P, int M, int nblk)
{
    __shared__ float4 ext[MAXBLK];
    __shared__ unsigned long long wred[4];

    const int t = threadIdx.x;
    const int m = blockIdx.x;
    const int b = blockIdx.y;

    for (int i = t; i < nblk; i += 256) ext[i] = bext[i];
    const float4 g = gt[(size_t)b * M + m];
    const float garea = (g.z - g.x) * (g.w - g.y);
    __syncthreads();

    // fallback key = (iou=0, p=0): all-zero column argmax -> index 0
    unsigned long long key = 0x00000000FFFFFFFFull;

    for (int c = 0; c < nblk; c++) {
        float4 e = ext[c];
        if (g.x >= e.z || g.z <= e.x || g.y >= e.w || g.w <= e.y) continue;
        int p = c * 256 + t;
        if (p >= P) continue;
        float4 d = sbox[p];
        float lx = fmaxf(d.x, g.x), ly = fmaxf(d.y, g.y);
        float rx = fminf(d.z, g.z), ry = fminf(d.w, g.w);
        float ww = fmaxf(rx - lx, 0.f), hh = fmaxf(ry - ly, 0.f);
        float inter = ww * hh;
        float darea = (d.z - d.x) * (d.w - d.y);
        float iou = inter * __builtin_amdgcn_rcpf(darea + garea - inter);
        if (iou > 0.0f) {
            unsigned orig = (unsigned)sperm[p];
            unsigned long long k = ((unsigned long long)__float_as_uint(iou) << 32)
                                 | (unsigned long long)(0xFFFFFFFFu - orig);
            if (k > key) key = k;
        }
    }

    for (int o = 32; o > 0; o >>= 1) {
        unsigned long long other = __shfl_xor(key, o, 64);
        if (other > key) key = other;
    }
    const int wv = t >> 6, lane = t & 63;
    if (lane == 0) wred[wv] = key;
    __syncthreads();
    if (t == 0) {
        unsigned long long k01 = wred[0] > wred[1] ? wred[0] : wred[1];
        unsigned long long k23 = wred[2] > wred[3] ? wred[2] : wred[3];
        bpkey[(size_t)b * M + m] = k01 > k23 ? k01 : k23;
    }
}

// ---------------------------------------------------------------------------
// force-match each GT's best prior (sequential: last-wins scatter).
// ---------------------------------------------------------------------------
__global__ void force_kernel(const unsigned long long* __restrict__ bpkey,
                             unsigned char* __restrict__ match, int P, int M)
{
    int b = blockIdx.x;
    if (threadIdx.x == 0) {
        for (int j = 0; j < M; j++) {
            unsigned p = 0xFFFFFFFFu - (unsigned)(bpkey[(size_t)b * M + j] & 0xFFFFFFFFull);
            match[(size_t)b * P + p] = (unsigned char)(0x80 | j);
        }
    }
}

// ---------------------------------------------------------------------------
// loss kernel: focal on every anchor (conf via coalesced LDS staging) +
// GIoU on positives. Per-block partials to private slots (no atomics).
// ---------------------------------------------------------------------------
__global__ __launch_bounds__(256)
void loss_kernel(const float4* __restrict__ locp,
                 const float*  __restrict__ conf,
                 const float4* __restrict__ dbox,
                 const float4* __restrict__ gt,
                 const int*    __restrict__ gtl,
                 const unsigned char* __restrict__ match,
                 double* __restrict__ partS,
                 int*    __restrict__ partC,
                 int P, int M)
{
    __shared__ float    scf[256 * CCLS];
    __shared__ float4   tb[MAXM];
    __shared__ int      tl[MAXM];
    __shared__ double   sv[4];
    __shared__ int      sc[4];

    const int t = threadIdx.x;
    const int b = blockIdx.y;
    const int p0 = blockIdx.x * 256;
    const int p = p0 + t;

    if (t < M) {
        tb[t] = gt[(size_t)b * M + t];
        tl[t] = gtl[(size_t)b * M + t];
    }

    const int cnt = min(256, P - p0);
    const int nf = cnt * CCLS;
    const float* src = conf + ((size_t)b * P + p0) * CCLS;
    {
        const int n4 = nf >> 2;
        const float4* s4 = (const float4*)src;
        float4* d4 = (float4*)scf;
        for (int i = t; i < n4; i += 256) d4[i] = s4[i];
        for (int i = (n4 << 2) + t; i < nf; i += 256) scf[i] = src[i];
    }
    __syncthreads();

    double acc = 0.0;
    int cnt_pos = 0;
    if (p < P) {
        unsigned char code = match[(size_t)b * P + p];
        int  idx = code & 0x3F;
        bool pos = (code & 0xC0) != 0;
        int  lbl = pos ? tl[idx] : 0;

        const float* x = scf + t * CCLS;
        float mx = -1e30f;
        #pragma unroll
        for (int c = 0; c < CCLS; c++) mx = fmaxf(mx, x[c]);
        float sum = 0.f;
        #pragma unroll
        for (int c = 0; c < CCLS; c++) sum += expf(x[c] - mx);
        float ce = (mx + logf(sum)) - x[lbl];
        float pt = expf(-ce);
        float om = 1.f - pt;
        acc = (double)(F_ALPHA * om * sqrtf(om) * ce);

        if (pos) {
            cnt_pos = 1;
            float4 d = dbox[p];
            float dw = d.z - d.x, dh = d.w - d.y;
            float dcx = d.x + dw * 0.5f, dcy = d.y + dh * 0.5f;
            float4 g = tb[idx];
            float gw = g.z - g.x, gh = g.w - g.y;
            float gcx = g.x + gw * 0.5f, gcy = g.y + gh * 0.5f;
            float ex = (gcx - dcx) / (dw + EPS8);
            float ey = (gcy - dcy) / (dh + EPS8);
            float ew = logf(gw / (dw + EPS8) + EPS8);
            float eh = logf(gh / (dh + EPS8) + EPS8);
            float tcx = ex * dw + dcx, tcy = ey * dh + dcy;
            float tw = expf(ew) * dw,  th = expf(eh) * dh;
            float t0 = tcx - tw * 0.5f, t1 = tcy - th * 0.5f;
            float t2 = tcx + tw * 0.5f, t3 = tcy + th * 0.5f;
            float4 l = locp[(size_t)b * P + p];
            float pcx = l.x * dw + dcx, pcy = l.y * dh + dcy;
            float pw = expf(l.z) * dw,  ph = expf(l.w) * dh;
            float q0 = pcx - pw * 0.5f, q1 = pcy - ph * 0.5f;
            float q2 = pcx + pw * 0.5f, q3 = pcy + ph * 0.5f;
            float ix0 = fmaxf(q0, t0), iy0 = fmaxf(q1, t1);
            float ix1 = fminf(q2, t2), iy1 = fminf(q3, t3);
            float iw = fmaxf(ix1 - ix0, 0.f), ih = fmaxf(iy1 - iy0, 0.f);
            float inter = iw * ih;
            float pa = (q2 - q0) * (q3 - q1);
            float ta = (t2 - t0) * (t3 - t1);
            float uni = pa + ta - inter;
            float iou = inter / (uni + EPS7);
            float e0 = fminf(q0, t0), e1 = fminf(q1, t1);
            float e2 = fmaxf(q2, t2), e3 = fmaxf(q3, t3);
            float ewd = fmaxf(e2 - e0, 0.f), ehd = fmaxf(e3 - e1, 0.f);
            float encl = ewd * ehd;
            float giou = iou - (encl - uni) / (encl + EPS7);
            acc += (double)(1.f - giou);
        }
    }

    for (int o = 32; o > 0; o >>= 1) {
        acc += __shfl_down(acc, o, 64);
        cnt_pos += __shfl_down(cnt_pos, o, 64);
    }
    int w = t >> 6, lane = t & 63;
    if (lane == 0) { sv[w] = acc; sc[w] = cnt_pos; }
    __syncthreads();
    if (t == 0) {
        int slot = blockIdx.y * gridDim.x + blockIdx.x;
        partS[slot] = sv[0] + sv[1] + sv[2] + sv[3];
        partC[slot] = sc[0] + sc[1] + sc[2] + sc[3];
    }
}

__global__ __launch_bounds__(256)
void final_kernel(const double* __restrict__ partS,
                  const int*    __restrict__ partC,
                  float* __restrict__ out, int n)
{
    __shared__ double sv[4];
    __shared__ long long sc[4];
    const int t = threadIdx.x;
    double a = 0.0; long long c = 0;
    for (int i = t; i < n; i += 256) { a += partS[i]; c += partC[i]; }
    for (int o = 32; o > 0; o >>= 1) {
        a += __shfl_down(a, o, 64);
        c += __shfl_down(c, o, 64);
    }
    int w = t >> 6, lane = t & 63;
    if (lane == 0) { sv[w] = a; sc[w] = c; }
    __syncthreads();
    if (t == 0) {
        double s = sv[0] + sv[1] + sv[2] + sv[3];
        long long np = sc[0] + sc[1] + sc[2] + sc[3];
        out[0] = (np == 0) ? 0.0f : (float)(s / (double)np);
    }
}

// ---------------------------------------------------------------------------
extern "C" void kernel_launch(void* const* d_in, const int* in_sizes, int n_in,
                              void* d_out, int out_size, void* d_ws, size_t ws_size,
                              hipStream_t stream)
{
    const float* locp = (const float*)d_in[0];   // [B,P,4]
    const float* conf = (const float*)d_in[1];   // [B,P,C]
    const float* dbox = (const float*)d_in[2];   // [P,4]
    const float* gt   = (const float*)d_in[3];   // [B,M,4]
    const int*   gtl  = (const int*)d_in[4];     // [B,M]

    const int P  = in_sizes[2] / 4;
    const long long BP = (long long)in_sizes[0] / 4;
    const int B  = (int)(BP / P);
    const int M  = in_sizes[4] / B;

    const int nblk = (P + 255) / 256;
    const int nPart = nblk * B;

    // ws layout (descending alignment):
    char* ws = (char*)d_ws;
    size_t off = 0;
    float4* sbox = (float4*)(ws + off);           off += (size_t)P * 16;
    float4* bext = (float4*)(ws + off);           off += (size_t)nblk * 16;
    unsigned long long* bpkey = (unsigned long long*)(ws + off); off += (size_t)B * M * 8;
    double* partS = (double*)(ws + off);          off += (size_t)nPart * 8;
    int* hist  = (int*)(ws + off);                off += (size_t)NBUCK * 4;
    int* offs  = (int*)(ws + off);                off += (size_t)NBUCK * 4;
    int* sperm = (int*)(ws + off);                off += (size_t)P * 4;
    int* partC = (int*)(ws + off);                off += (size_t)nPart * 4;
    unsigned char* match = (unsigned char*)(ws + off);

    hipMemsetAsync(hist, 0, NBUCK * 4, stream);

    dim3 grid(nblk, B);
    histo_kernel<<<nblk, 256, 0, stream>>>((const float4*)dbox, hist, P);
    scan_kernel<<<1, NBUCK, 0, stream>>>(hist, offs);
    scatter_kernel<<<nblk, 256, 0, stream>>>((const float4*)dbox, offs, sbox, sperm, P);
    extent_kernel<<<nblk, 256, 0, stream>>>(sbox, bext, P);
    bt_kernel<<<grid, 256, 0, stream>>>(sbox, sperm, (const float4*)gt, bext,
                                        match, P, M);
    bp_kernel<<<dim3(M, B), 256, 0, stream>>>(sbox, sperm, (const float4*)gt, bext,
                                              bpkey, P, M, nblk);
    force_kernel<<<B, 64, 0, stream>>>(bpkey, match, P, M);
    loss_kernel<<<grid, 256, 0, stream>>>((const float4*)locp, conf,
                                          (const float4*)dbox, (const float4*)gt,
                                          gtl, match, partS, partC, P, M);
    final_kernel<<<1, 256, 0, stream>>>(partS, partC, (float*)d_out, nPart);
}